// Round 1
// baseline (889.601 us; speedup 1.0000x reference)
//
#include <hip/hip_runtime.h>
#include <math.h>

#define BATCH 4096
#define D 784
#define N 10000

#define TM 64
#define TN 128
#define KC 16
#define NCHUNK ((N + TN - 1) / TN)   // 79

// ---------------------------------------------------------------------------
// Kernel 1: wsq[n] = sum_d w[n][d]^2   (one wave per codebook row)
// ---------------------------------------------------------------------------
__global__ __launch_bounds__(256) void wsq_kernel(const float* __restrict__ w,
                                                  float* __restrict__ wsq) {
    int row = blockIdx.x * 4 + (threadIdx.x >> 6);
    int lane = threadIdx.x & 63;
    if (row >= N) return;
    const float4* wr4 = (const float4*)(w + (size_t)row * D);
    float s = 0.f;
    for (int i = lane; i < D / 4; i += 64) {
        float4 v = wr4[i];
        s += v.x * v.x + v.y * v.y + v.z * v.z + v.w * v.w;
    }
    #pragma unroll
    for (int off = 32; off; off >>= 1) s += __shfl_down(s, off);
    if (lane == 0) wsq[row] = s;
}

// ---------------------------------------------------------------------------
// Kernel 2: per-(row, 128-col chunk) partial argmin of  wsq[c] - 2*x.w
// 64x128 tile per block, 256 threads, 4x8 micro-tile, K staged in LDS k-major.
// ---------------------------------------------------------------------------
__global__ __launch_bounds__(256) void dist_argmin_kernel(
    const float* __restrict__ x, const float* __restrict__ w,
    const float* __restrict__ wsq, float2* __restrict__ partial) {
    // k-major tiles; pitches multiple of 4 (aligned float4 reads), ~2-way banks
    __shared__ float xs[KC][68];
    __shared__ float wsh[KC][132];

    int tid = threadIdx.x;
    int rowBase = blockIdx.y * TM;
    int colBase = blockIdx.x * TN;

    int tr = tid >> 4;  // 0..15 -> rows tr*4..tr*4+3
    int tc = tid & 15;  // 0..15 -> cols tc*8..tc*8+7

    float acc[4][8];
    #pragma unroll
    for (int i = 0; i < 4; i++)
        #pragma unroll
        for (int j = 0; j < 8; j++) acc[i][j] = 0.f;

    int xrow = tid >> 2;  // 0..63
    int xseg = tid & 3;   // 0..3
    int wr0 = tid >> 2;   // 0..63 (second half: +64)
    int wseg = tid & 3;

    for (int k0 = 0; k0 < D; k0 += KC) {
        // ---- issue global loads (regs) ----
        float4 xv = *(const float4*)&x[(size_t)(rowBase + xrow) * D + k0 + xseg * 4];
        int c0 = colBase + wr0;
        int c1 = colBase + wr0 + 64;
        float4 wv0 = (c0 < N) ? *(const float4*)&w[(size_t)c0 * D + k0 + wseg * 4]
                              : make_float4(0.f, 0.f, 0.f, 0.f);
        float4 wv1 = (c1 < N) ? *(const float4*)&w[(size_t)c1 * D + k0 + wseg * 4]
                              : make_float4(0.f, 0.f, 0.f, 0.f);

        __syncthreads();  // previous iteration's LDS reads done

        // ---- transposed stores into k-major tiles ----
        xs[xseg * 4 + 0][xrow] = xv.x;
        xs[xseg * 4 + 1][xrow] = xv.y;
        xs[xseg * 4 + 2][xrow] = xv.z;
        xs[xseg * 4 + 3][xrow] = xv.w;

        wsh[wseg * 4 + 0][wr0] = wv0.x;
        wsh[wseg * 4 + 1][wr0] = wv0.y;
        wsh[wseg * 4 + 2][wr0] = wv0.z;
        wsh[wseg * 4 + 3][wr0] = wv0.w;
        wsh[wseg * 4 + 0][wr0 + 64] = wv1.x;
        wsh[wseg * 4 + 1][wr0 + 64] = wv1.y;
        wsh[wseg * 4 + 2][wr0 + 64] = wv1.z;
        wsh[wseg * 4 + 3][wr0 + 64] = wv1.w;

        __syncthreads();

        // ---- 4x8 FMA micro-kernel over KC ----
        #pragma unroll
        for (int k = 0; k < KC; k++) {
            float4 a = *(const float4*)&xs[k][tr * 4];
            float4 b0 = *(const float4*)&wsh[k][tc * 8];
            float4 b1 = *(const float4*)&wsh[k][tc * 8 + 4];
            float xa[4] = {a.x, a.y, a.z, a.w};
            float wb[8] = {b0.x, b0.y, b0.z, b0.w, b1.x, b1.y, b1.z, b1.w};
            #pragma unroll
            for (int i = 0; i < 4; i++)
                #pragma unroll
                for (int j = 0; j < 8; j++)
                    acc[i][j] = fmaf(xa[i], wb[j], acc[i][j]);
        }
    }

    // ---- epilogue: dist = wsq - 2*cross; per-row argmin over this chunk ----
    float bestv[4];
    int besti[4];
    #pragma unroll
    for (int i = 0; i < 4; i++) { bestv[i] = INFINITY; besti[i] = 0x7fffffff; }

    #pragma unroll
    for (int j = 0; j < 8; j++) {
        int c = colBase + tc * 8 + j;
        float wq = (c < N) ? wsq[c] : INFINITY;
        #pragma unroll
        for (int i = 0; i < 4; i++) {
            float dv = wq - 2.f * acc[i][j];
            if (dv < bestv[i] || (dv == bestv[i] && c < besti[i])) {
                bestv[i] = dv; besti[i] = c;
            }
        }
    }
    // reduce across the 16 col-lanes (lane bits 0..3)
    #pragma unroll
    for (int off = 1; off < 16; off <<= 1) {
        #pragma unroll
        for (int i = 0; i < 4; i++) {
            float ov = __shfl_xor(bestv[i], off);
            int oi = __shfl_xor(besti[i], off);
            if (ov < bestv[i] || (ov == bestv[i] && oi < besti[i])) {
                bestv[i] = ov; besti[i] = oi;
            }
        }
    }
    if (tc == 0) {
        #pragma unroll
        for (int i = 0; i < 4; i++) {
            int r = rowBase + tr * 4 + i;
            partial[(size_t)r * NCHUNK + blockIdx.x] =
                make_float2(bestv[i], __int_as_float(besti[i]));
        }
    }
}

// ---------------------------------------------------------------------------
// Kernel 3: per-row reduce over 79 chunks, then gather weights[bmu] -> out
// ---------------------------------------------------------------------------
__global__ __launch_bounds__(256) void reduce_gather_kernel(
    const float2* __restrict__ partial, const float* __restrict__ w,
    float* __restrict__ out) {
    int row = blockIdx.x;
    int tid = threadIdx.x;
    __shared__ int s_idx;

    if (tid < 64) {
        float bv = INFINITY;
        int bi = 0x7fffffff;
        for (int c = tid; c < NCHUNK; c += 64) {
            float2 p = partial[(size_t)row * NCHUNK + c];
            int pi = __float_as_int(p.y);
            if (p.x < bv || (p.x == bv && pi < bi)) { bv = p.x; bi = pi; }
        }
        #pragma unroll
        for (int off = 32; off; off >>= 1) {
            float ov = __shfl_down(bv, off);
            int oi = __shfl_down(bi, off);
            if (ov < bv || (ov == bv && oi < bi)) { bv = ov; bi = oi; }
        }
        if (tid == 0) s_idx = bi;
    }
    __syncthreads();
    int idx = s_idx;

    const float4* src = (const float4*)&w[(size_t)idx * D];
    float4* dst = (float4*)&out[(size_t)row * D];
    for (int i = tid; i < D / 4; i += 256) dst[i] = src[i];
}

// ---------------------------------------------------------------------------
extern "C" void kernel_launch(void* const* d_in, const int* in_sizes, int n_in,
                              void* d_out, int out_size, void* d_ws, size_t ws_size,
                              hipStream_t stream) {
    const float* x = (const float*)d_in[0];
    const float* w = (const float*)d_in[1];
    float* out = (float*)d_out;

    float* wsq = (float*)d_ws;                              // N floats
    float2* partial = (float2*)((char*)d_ws + 65536);       // 4096*79 float2

    hipLaunchKernelGGL(wsq_kernel, dim3((N + 3) / 4), dim3(256), 0, stream, w, wsq);
    hipLaunchKernelGGL(dist_argmin_kernel, dim3(NCHUNK, BATCH / TM), dim3(256), 0,
                       stream, x, w, wsq, partial);
    hipLaunchKernelGGL(reduce_gather_kernel, dim3(BATCH), dim3(256), 0, stream,
                       partial, w, out);
}

// Round 2
// 526.174 us; speedup vs baseline: 1.6907x; 1.6907x over previous
//
#include <hip/hip_runtime.h>
#include <math.h>

#define BATCH 4096
#define D 784
#define N 10000

#define KP 800        // padded K (bf16 elements) in staging buffers
#define NPAD 10112    // 79 * 128
#define NCHUNK 79
#define BM 128
#define BN 128
#define BK 32
#define KPL 40        // LDS row pitch in halves (80 B) -> ~2-way banks on b128
#define MARGIN 3.0f

typedef __attribute__((ext_vector_type(8))) short bh8;
typedef __attribute__((ext_vector_type(4))) float fx4;

static __device__ __forceinline__ unsigned short f2bf(float f) {
    unsigned u = __float_as_uint(f);
    unsigned r = u + 0x7fffu + ((u >> 16) & 1u);   // round-to-nearest-even
    return (unsigned short)(r >> 16);
}

static __device__ __forceinline__ void top2_insert(float w, int j, float& v0, int& i0,
                                                   float& v1, int& i1) {
    if (w < v0 || (w == v0 && j < i0)) { v1 = v0; i1 = i0; v0 = w; i0 = j; }
    else if (w < v1 || (w == v1 && j < i1)) { v1 = w; i1 = j; }
}

// ---------------------------------------------------------------------------
// bf16 conversion of x with K zero-pad to 800
// ---------------------------------------------------------------------------
__global__ __launch_bounds__(256) void convert_x_kernel(const float* __restrict__ x,
                                                        unsigned short* __restrict__ xh) {
    int row = blockIdx.x;
    const float4* xr = (const float4*)(x + (size_t)row * D);
    unsigned short* dst = xh + (size_t)row * KP;
    for (int i = threadIdx.x; i < KP / 4; i += 256) {
        int k = i * 4;
        uint2 o;
        if (k < D) {
            float4 v = xr[i];
            o.x = (unsigned)f2bf(v.x) | ((unsigned)f2bf(v.y) << 16);
            o.y = (unsigned)f2bf(v.z) | ((unsigned)f2bf(v.w) << 16);
        } else { o.x = 0u; o.y = 0u; }
        *(uint2*)(dst + k) = o;
    }
}

// ---------------------------------------------------------------------------
// bf16 conversion of w (rows padded to 10112 with zeros) + fp32 wsq (pad=+INF)
// ---------------------------------------------------------------------------
__global__ __launch_bounds__(256) void convert_w_kernel(const float* __restrict__ w,
                                                        unsigned short* __restrict__ wh,
                                                        float* __restrict__ wsq) {
    int row = blockIdx.x;
    unsigned short* dst = wh + (size_t)row * KP;
    float s = 0.f;
    if (row < N) {
        const float4* wr = (const float4*)(w + (size_t)row * D);
        for (int i = threadIdx.x; i < KP / 4; i += 256) {
            int k = i * 4;
            uint2 o;
            if (k < D) {
                float4 v = wr[i];
                s += v.x * v.x + v.y * v.y + v.z * v.z + v.w * v.w;
                o.x = (unsigned)f2bf(v.x) | ((unsigned)f2bf(v.y) << 16);
                o.y = (unsigned)f2bf(v.z) | ((unsigned)f2bf(v.w) << 16);
            } else { o.x = 0u; o.y = 0u; }
            *(uint2*)(dst + k) = o;
        }
    } else {
        for (int i = threadIdx.x; i < KP / 4; i += 256) {
            uint2 o; o.x = 0u; o.y = 0u;
            *(uint2*)(dst + i * 4) = o;
        }
    }
    __shared__ float sred[4];
    #pragma unroll
    for (int off = 32; off; off >>= 1) s += __shfl_down(s, off);
    if ((threadIdx.x & 63) == 0) sred[threadIdx.x >> 6] = s;
    __syncthreads();
    if (threadIdx.x == 0) {
        float t = sred[0] + sred[1] + sred[2] + sred[3];
        wsq[row] = (row < N) ? t : INFINITY;
    }
}

// ---------------------------------------------------------------------------
// MFMA distance kernel: per (128-row, 128-col) block, top-2 (val,idx) per row
// dist = wsq[c] - 2 * (x . w)   (x_sq row-constant, argmin-invariant)
// ---------------------------------------------------------------------------
__global__ __launch_bounds__(256) void dist_mfma_kernel(
    const unsigned short* __restrict__ xh, const unsigned short* __restrict__ wh,
    const float* __restrict__ wsq, float4* __restrict__ partial) {
    __shared__ __align__(16) unsigned short as_[BM][KPL];
    __shared__ __align__(16) unsigned short bs_[BN][KPL];
    __shared__ float4 red[BM][2];

    int tid = threadIdx.x;
    int lane = tid & 63;
    int wid = tid >> 6;
    int waveM = (wid >> 1) * 64;
    int waveN = (wid & 1) * 64;
    int rowBase = blockIdx.y * BM;
    int colBase = blockIdx.x * BN;

    fx4 acc[4][4];
    #pragma unroll
    for (int m = 0; m < 4; m++)
        #pragma unroll
        for (int n = 0; n < 4; n++) acc[m][n] = (fx4)0.f;

    int lrow = tid >> 1;       // 0..127
    int lseg = tid & 1;        // 0..1  (each thread stages 32 B of a 64 B row)
    const unsigned short* xsrc = xh + (size_t)(rowBase + lrow) * KP + lseg * 16;
    const unsigned short* wsrc = wh + (size_t)(colBase + lrow) * KP + lseg * 16;

    for (int k0 = 0; k0 < KP; k0 += BK) {
        uint4 xa = *(const uint4*)(xsrc + k0);
        uint4 xb = *(const uint4*)(xsrc + k0 + 8);
        uint4 wa = *(const uint4*)(wsrc + k0);
        uint4 wb = *(const uint4*)(wsrc + k0 + 8);
        __syncthreads();   // previous iteration's LDS reads complete
        *(uint4*)&as_[lrow][lseg * 16]     = xa;
        *(uint4*)&as_[lrow][lseg * 16 + 8] = xb;
        *(uint4*)&bs_[lrow][lseg * 16]     = wa;
        *(uint4*)&bs_[lrow][lseg * 16 + 8] = wb;
        __syncthreads();

        bh8 af[4], bf[4];
        #pragma unroll
        for (int m = 0; m < 4; m++)
            af[m] = *(const bh8*)&as_[waveM + m * 16 + (lane & 15)][(lane >> 4) * 8];
        #pragma unroll
        for (int n = 0; n < 4; n++)
            bf[n] = *(const bh8*)&bs_[waveN + n * 16 + (lane & 15)][(lane >> 4) * 8];
        #pragma unroll
        for (int m = 0; m < 4; m++)
            #pragma unroll
            for (int n = 0; n < 4; n++)
                acc[m][n] = __builtin_amdgcn_mfma_f32_16x16x32_bf16(af[m], bf[n],
                                                                    acc[m][n], 0, 0, 0);
    }

    // ---- epilogue: per-row top-2 over this block's 128 cols ----
    float wq[4];
    #pragma unroll
    for (int n = 0; n < 4; n++)
        wq[n] = wsq[colBase + waveN + n * 16 + (lane & 15)];

    int h = lane >> 4;
    #pragma unroll
    for (int m = 0; m < 4; m++) {
        #pragma unroll
        for (int r = 0; r < 4; r++) {
            int row_local = waveM + m * 16 + h * 4 + r;
            float v0 = INFINITY, v1 = INFINITY;
            int i0 = 0x7fffffff, i1 = 0x7fffffff;
            #pragma unroll
            for (int n = 0; n < 4; n++) {
                float dv = wq[n] - 2.f * acc[m][n][r];
                int ci = colBase + waveN + n * 16 + (lane & 15);
                top2_insert(dv, ci, v0, i0, v1, i1);
            }
            #pragma unroll
            for (int mask = 1; mask < 16; mask <<= 1) {
                float w0 = __shfl_xor(v0, mask); int j0 = __shfl_xor(i0, mask);
                float w1 = __shfl_xor(v1, mask); int j1 = __shfl_xor(i1, mask);
                top2_insert(w0, j0, v0, i0, v1, i1);
                top2_insert(w1, j1, v0, i0, v1, i1);
            }
            if ((lane & 15) == 0)
                red[row_local][wid & 1] =
                    make_float4(v0, __int_as_float(i0), v1, __int_as_float(i1));
        }
    }
    __syncthreads();
    if (tid < BM) {
        float4 pa = red[tid][0], pb = red[tid][1];
        float v0 = pa.x, v1 = pa.z;
        int i0 = __float_as_int(pa.y), i1 = __float_as_int(pa.w);
        top2_insert(pb.x, __float_as_int(pb.y), v0, i0, v1, i1);
        top2_insert(pb.z, __float_as_int(pb.w), v0, i0, v1, i1);
        partial[(size_t)(rowBase + tid) * NCHUNK + blockIdx.x] =
            make_float4(v0, __int_as_float(i0), v1, __int_as_float(i1));
    }
}

// ---------------------------------------------------------------------------
// Rescue: approx global min per row, exact fp64 rescore of candidates within
// MARGIN, tie-break lowest index, gather winning weight row. One wave per row.
// ---------------------------------------------------------------------------
__global__ __launch_bounds__(256) void rescore_kernel(const float* __restrict__ x,
                                                      const float* __restrict__ w,
                                                      const float4* __restrict__ partial,
                                                      float* __restrict__ out) {
    int wid = threadIdx.x >> 6, lane = threadIdx.x & 63;
    int row = blockIdx.x * 4 + wid;
    __shared__ int s_cnt[4];
    __shared__ int s_cand[4][64];

    const float4* part = partial + (size_t)row * NCHUNK;

    float bv = INFINITY;
    for (int c = lane; c < NCHUNK; c += 64) bv = fminf(bv, part[c].x);
    #pragma unroll
    for (int mask = 1; mask < 64; mask <<= 1) bv = fminf(bv, __shfl_xor(bv, mask));
    float thr = bv + MARGIN;

    if (lane == 0) s_cnt[wid] = 0;
    __syncthreads();
    for (int c = lane; c < NCHUNK; c += 64) {
        float4 p = part[c];
        if (p.x <= thr) {
            int pos = atomicAdd(&s_cnt[wid], 1);
            if (pos < 64) s_cand[wid][pos] = __float_as_int(p.y);
        }
        if (p.z <= thr) {
            int pos = atomicAdd(&s_cnt[wid], 1);
            if (pos < 64) s_cand[wid][pos] = __float_as_int(p.w);
        }
    }
    __syncthreads();
    int cnt = s_cnt[wid]; if (cnt > 64) cnt = 64;

    double bd = INFINITY; int bi = 0x7fffffff;
    for (int c = 0; c < cnt; c++) {
        int idx = s_cand[wid][c];
        const float* wr = w + (size_t)idx * D;
        const float* xr = x + (size_t)row * D;
        double s = 0.0;
        for (int d = lane; d < D; d += 64) {
            double wv = (double)wr[d];
            s += wv * (wv - 2.0 * (double)xr[d]);
        }
        #pragma unroll
        for (int mask = 1; mask < 64; mask <<= 1) s += __shfl_xor(s, mask);
        if (s < bd || (s == bd && idx < bi)) { bd = s; bi = idx; }
    }

    const float4* src = (const float4*)(w + (size_t)bi * D);
    float4* dst = (float4*)(out + (size_t)row * D);
    for (int i = lane; i < D / 4; i += 64) dst[i] = src[i];
}

// ---------------------------------------------------------------------------
// Fallback fp32 path (round-1 kernels) in case ws_size is too small
// ---------------------------------------------------------------------------
#define FTM 64
#define FTN 128
#define FKC 16
#define FNCHUNK ((N + FTN - 1) / FTN)

__global__ __launch_bounds__(256) void wsq_kernel(const float* __restrict__ w,
                                                  float* __restrict__ wsq) {
    int row = blockIdx.x * 4 + (threadIdx.x >> 6);
    int lane = threadIdx.x & 63;
    if (row >= N) return;
    const float4* wr4 = (const float4*)(w + (size_t)row * D);
    float s = 0.f;
    for (int i = lane; i < D / 4; i += 64) {
        float4 v = wr4[i];
        s += v.x * v.x + v.y * v.y + v.z * v.z + v.w * v.w;
    }
    #pragma unroll
    for (int off = 32; off; off >>= 1) s += __shfl_down(s, off);
    if (lane == 0) wsq[row] = s;
}

__global__ __launch_bounds__(256) void dist_argmin_kernel(
    const float* __restrict__ x, const float* __restrict__ w,
    const float* __restrict__ wsq, float2* __restrict__ partial) {
    __shared__ float xs[FKC][68];
    __shared__ float wsh[FKC][132];
    int tid = threadIdx.x;
    int rowBase = blockIdx.y * FTM;
    int colBase = blockIdx.x * FTN;
    int tr = tid >> 4, tc = tid & 15;
    float acc[4][8];
    #pragma unroll
    for (int i = 0; i < 4; i++)
        #pragma unroll
        for (int j = 0; j < 8; j++) acc[i][j] = 0.f;
    int xrow = tid >> 2, xseg = tid & 3;
    for (int k0 = 0; k0 < D; k0 += FKC) {
        float4 xv = *(const float4*)&x[(size_t)(rowBase + xrow) * D + k0 + xseg * 4];
        int c0 = colBase + xrow, c1 = colBase + xrow + 64;
        float4 wv0 = (c0 < N) ? *(const float4*)&w[(size_t)c0 * D + k0 + xseg * 4]
                              : make_float4(0.f, 0.f, 0.f, 0.f);
        float4 wv1 = (c1 < N) ? *(const float4*)&w[(size_t)c1 * D + k0 + xseg * 4]
                              : make_float4(0.f, 0.f, 0.f, 0.f);
        __syncthreads();
        xs[xseg * 4 + 0][xrow] = xv.x; xs[xseg * 4 + 1][xrow] = xv.y;
        xs[xseg * 4 + 2][xrow] = xv.z; xs[xseg * 4 + 3][xrow] = xv.w;
        wsh[xseg * 4 + 0][xrow] = wv0.x; wsh[xseg * 4 + 1][xrow] = wv0.y;
        wsh[xseg * 4 + 2][xrow] = wv0.z; wsh[xseg * 4 + 3][xrow] = wv0.w;
        wsh[xseg * 4 + 0][xrow + 64] = wv1.x; wsh[xseg * 4 + 1][xrow + 64] = wv1.y;
        wsh[xseg * 4 + 2][xrow + 64] = wv1.z; wsh[xseg * 4 + 3][xrow + 64] = wv1.w;
        __syncthreads();
        #pragma unroll
        for (int k = 0; k < FKC; k++) {
            float4 a = *(const float4*)&xs[k][tr * 4];
            float4 b0 = *(const float4*)&wsh[k][tc * 8];
            float4 b1 = *(const float4*)&wsh[k][tc * 8 + 4];
            float xa[4] = {a.x, a.y, a.z, a.w};
            float wb[8] = {b0.x, b0.y, b0.z, b0.w, b1.x, b1.y, b1.z, b1.w};
            #pragma unroll
            for (int i = 0; i < 4; i++)
                #pragma unroll
                for (int j = 0; j < 8; j++) acc[i][j] = fmaf(xa[i], wb[j], acc[i][j]);
        }
    }
    float bestv[4]; int besti[4];
    #pragma unroll
    for (int i = 0; i < 4; i++) { bestv[i] = INFINITY; besti[i] = 0x7fffffff; }
    #pragma unroll
    for (int j = 0; j < 8; j++) {
        int c = colBase + tc * 8 + j;
        float wqv = (c < N) ? wsq[c] : INFINITY;
        #pragma unroll
        for (int i = 0; i < 4; i++) {
            float dv = wqv - 2.f * acc[i][j];
            if (dv < bestv[i] || (dv == bestv[i] && c < besti[i])) { bestv[i] = dv; besti[i] = c; }
        }
    }
    #pragma unroll
    for (int off = 1; off < 16; off <<= 1) {
        #pragma unroll
        for (int i = 0; i < 4; i++) {
            float ov = __shfl_xor(bestv[i], off);
            int oi = __shfl_xor(besti[i], off);
            if (ov < bestv[i] || (ov == bestv[i] && oi < besti[i])) { bestv[i] = ov; besti[i] = oi; }
        }
    }
    if (tc == 0)
        #pragma unroll
        for (int i = 0; i < 4; i++)
            partial[(size_t)(rowBase + tr * 4 + i) * FNCHUNK + blockIdx.x] =
                make_float2(bestv[i], __int_as_float(besti[i]));
}

__global__ __launch_bounds__(256) void reduce_gather_kernel(
    const float2* __restrict__ partial, const float* __restrict__ w,
    float* __restrict__ out) {
    int row = blockIdx.x, tid = threadIdx.x;
    __shared__ int s_idx;
    if (tid < 64) {
        float bv2 = INFINITY; int bi2 = 0x7fffffff;
        for (int c = tid; c < FNCHUNK; c += 64) {
            float2 p = partial[(size_t)row * FNCHUNK + c];
            int pi = __float_as_int(p.y);
            if (p.x < bv2 || (p.x == bv2 && pi < bi2)) { bv2 = p.x; bi2 = pi; }
        }
        #pragma unroll
        for (int off = 32; off; off >>= 1) {
            float ov = __shfl_down(bv2, off);
            int oi = __shfl_down(bi2, off);
            if (ov < bv2 || (ov == bv2 && oi < bi2)) { bv2 = ov; bi2 = oi; }
        }
        if (tid == 0) s_idx = bi2;
    }
    __syncthreads();
    int idx = s_idx;
    const float4* src = (const float4*)&w[(size_t)idx * D];
    float4* dst = (float4*)&out[(size_t)row * D];
    for (int i = tid; i < D / 4; i += 256) dst[i] = src[i];
}

// ---------------------------------------------------------------------------
extern "C" void kernel_launch(void* const* d_in, const int* in_sizes, int n_in,
                              void* d_out, int out_size, void* d_ws, size_t ws_size,
                              hipStream_t stream) {
    const float* x = (const float*)d_in[0];
    const float* w = (const float*)d_in[1];
    float* out = (float*)d_out;

    // ws layout (fast path)
    const size_t off_xh = 0;
    const size_t off_wh = off_xh + (size_t)BATCH * KP * 2;          // 6,553,600
    const size_t off_wsq = off_wh + (size_t)NPAD * KP * 2;          // 22,732,800
    const size_t off_part = off_wsq + (size_t)NPAD * 4 + 3648;      // align to 16
    const size_t need = off_part + (size_t)BATCH * NCHUNK * 16;

    if (ws_size >= need) {
        unsigned short* xh = (unsigned short*)((char*)d_ws + off_xh);
        unsigned short* wh = (unsigned short*)((char*)d_ws + off_wh);
        float* wsq = (float*)((char*)d_ws + off_wsq);
        float4* partial = (float4*)((char*)d_ws + off_part);

        hipLaunchKernelGGL(convert_x_kernel, dim3(BATCH), dim3(256), 0, stream, x, xh);
        hipLaunchKernelGGL(convert_w_kernel, dim3(NPAD), dim3(256), 0, stream, w, wh, wsq);
        hipLaunchKernelGGL(dist_mfma_kernel, dim3(NCHUNK, BATCH / BM), dim3(256), 0,
                           stream, xh, wh, wsq, partial);
        hipLaunchKernelGGL(rescore_kernel, dim3(BATCH / 4), dim3(256), 0, stream,
                           x, w, partial, out);
    } else {
        float* wsq = (float*)d_ws;
        float2* partial = (float2*)((char*)d_ws + 65536);
        hipLaunchKernelGGL(wsq_kernel, dim3((N + 3) / 4), dim3(256), 0, stream, w, wsq);
        hipLaunchKernelGGL(dist_argmin_kernel, dim3(FNCHUNK, BATCH / FTM), dim3(256), 0,
                           stream, x, w, wsq, partial);
        hipLaunchKernelGGL(reduce_gather_kernel, dim3(BATCH), dim3(256), 0, stream,
                           partial, w, out);
    }
}

// Round 3
// 472.720 us; speedup vs baseline: 1.8819x; 1.1131x over previous
//
#include <hip/hip_runtime.h>
#include <math.h>

#define BATCH 4096
#define D 784
#define N 10000

#define KP 800                 // padded K (halves)
#define BK 32                  // K-step
#define KT (KP / BK)           // 25
#define BM 128
#define BN 128
#define CPB 4                  // 128-col chunks swept per block
#define GX 20                  // blocks along N
#define NG GX                  // partial groups per row
#define NPAD (GX * CPB * BN)   // 10240
#define MARGIN 3.0f

typedef __attribute__((ext_vector_type(8))) short bh8;
typedef __attribute__((ext_vector_type(4))) float fx4;
typedef const __attribute__((address_space(1))) void CGV;
typedef __attribute__((address_space(3))) void LDSV;

static __device__ __forceinline__ unsigned short f2bf(float f) {
    unsigned u = __float_as_uint(f);
    unsigned r = u + 0x7fffu + ((u >> 16) & 1u);
    return (unsigned short)(r >> 16);
}

static __device__ __forceinline__ void top2_insert(float w, int j, float& v0, int& i0,
                                                   float& v1, int& i1) {
    if (w < v0 || (w == v0 && j < i0)) { v1 = v0; i1 = i0; v0 = w; i0 = j; }
    else if (w < v1 || (w == v1 && j < i1)) { v1 = w; i1 = j; }
}

// ---------------------------------------------------------------------------
__global__ __launch_bounds__(256) void convert_x_kernel(const float* __restrict__ x,
                                                        unsigned short* __restrict__ xh) {
    int row = blockIdx.x;
    const float4* xr = (const float4*)(x + (size_t)row * D);
    unsigned short* dst = xh + (size_t)row * KP;
    for (int i = threadIdx.x; i < KP / 4; i += 256) {
        int k = i * 4;
        uint2 o;
        if (k < D) {
            float4 v = xr[i];
            o.x = (unsigned)f2bf(v.x) | ((unsigned)f2bf(v.y) << 16);
            o.y = (unsigned)f2bf(v.z) | ((unsigned)f2bf(v.w) << 16);
        } else { o.x = 0u; o.y = 0u; }
        *(uint2*)(dst + k) = o;
    }
}

__global__ __launch_bounds__(256) void convert_w_kernel(const float* __restrict__ w,
                                                        unsigned short* __restrict__ wh,
                                                        float* __restrict__ wsq) {
    int row = blockIdx.x;
    unsigned short* dst = wh + (size_t)row * KP;
    float s = 0.f;
    if (row < N) {
        const float4* wr = (const float4*)(w + (size_t)row * D);
        for (int i = threadIdx.x; i < KP / 4; i += 256) {
            int k = i * 4;
            uint2 o;
            if (k < D) {
                float4 v = wr[i];
                s += v.x * v.x + v.y * v.y + v.z * v.z + v.w * v.w;
                o.x = (unsigned)f2bf(v.x) | ((unsigned)f2bf(v.y) << 16);
                o.y = (unsigned)f2bf(v.z) | ((unsigned)f2bf(v.w) << 16);
            } else { o.x = 0u; o.y = 0u; }
            *(uint2*)(dst + k) = o;
        }
    } else {
        for (int i = threadIdx.x; i < KP / 4; i += 256) {
            uint2 o; o.x = 0u; o.y = 0u;
            *(uint2*)(dst + i * 4) = o;
        }
    }
    __shared__ float sred[4];
    #pragma unroll
    for (int off = 32; off; off >>= 1) s += __shfl_down(s, off);
    if ((threadIdx.x & 63) == 0) sred[threadIdx.x >> 6] = s;
    __syncthreads();
    if (threadIdx.x == 0) {
        float t = sred[0] + sred[1] + sred[2] + sred[3];
        wsq[row] = (row < N) ? t : INFINITY;
    }
}

// ---------------------------------------------------------------------------
// MFMA distance kernel. 128x128 tile, 4 waves, double-buffered global_load_lds
// staging (T3-minimum 2-phase), XOR slot-swizzle both-sides, per-block sweep of
// CPB col-chunks with register-resident running top-2 per row.
// ---------------------------------------------------------------------------
__global__ __launch_bounds__(256, 2) void dist_mfma_kernel(
    const unsigned short* __restrict__ xh, const unsigned short* __restrict__ wh,
    const float* __restrict__ wsq, float4* __restrict__ partial) {
    __shared__ __align__(16) unsigned short As[2][BM * BK];
    __shared__ __align__(16) unsigned short Bs[2][BN * BK];
    __shared__ float4 red[BM][2];

    const int tid = threadIdx.x;
    const int lane = tid & 63;
    const int wid = tid >> 6;
    const int waveM = (wid >> 1) * 64;
    const int waveN = (wid & 1) * 64;

    // XCD-aware remap: dispatch id L -> work id G so that 32 consecutive G
    // (same bx => same B panel) land on one XCD. 640 = 8 * 80, bijective.
    const int L = blockIdx.x + GX * blockIdx.y;
    const int G = (L & 7) * 80 + (L >> 3);
    const int bx = G >> 5;          // 0..19
    const int by = G & 31;          // 0..31
    const int rowBase = by * BM;
    const int colBase0 = bx * (CPB * BN);

    // staging source mapping: physical slot p = j*256 + tid; row = j*64 + rr,
    // phys slotcol = tid&3; logical slotcol = (tid&3) ^ f(row), f(r)=(r>>1)&3
    // (f(r) invariant under r += 64, so one csw serves both j calls)
    const int rr = tid >> 2;
    const int csw = (tid & 3) ^ ((rr >> 1) & 3);
    const unsigned short* aSrc0 = xh + (size_t)(rowBase + rr) * KP + csw * 8;
    const unsigned short* aSrc1 = aSrc0 + (size_t)64 * KP;

    char* ldsA0 = (char*)&As[0][0] + wid * 1024;
    char* ldsA1 = (char*)&As[1][0] + wid * 1024;
    char* ldsB0 = (char*)&Bs[0][0] + wid * 1024;
    char* ldsB1 = (char*)&Bs[1][0] + wid * 1024;

    // fragment read offsets (halves), swizzled to match staging
    int offA[4], offB[4];
    #pragma unroll
    for (int m = 0; m < 4; m++) {
        int r = waveM + m * 16 + (lane & 15);
        offA[m] = r * BK + (((lane >> 4) ^ ((r >> 1) & 3)) << 3);
    }
    #pragma unroll
    for (int n = 0; n < 4; n++) {
        int r = waveN + n * 16 + (lane & 15);
        offB[n] = r * BK + (((lane >> 4) ^ ((r >> 1) & 3)) << 3);
    }

    // running per-lane top-2 for 16 (m,r) rows
    float V0[16], V1[16];
    int I0[16], I1[16];
    #pragma unroll
    for (int q = 0; q < 16; q++) {
        V0[q] = INFINITY; V1[q] = INFINITY;
        I0[q] = 0x7fffffff; I1[q] = 0x7fffffff;
    }

#define STAGE(nb, k0)                                                                  \
    do {                                                                               \
        __builtin_amdgcn_global_load_lds((CGV*)(aSrc0 + (k0)), (LDSV*)(ldsA##nb), 16, 0, 0);        \
        __builtin_amdgcn_global_load_lds((CGV*)(aSrc1 + (k0)), (LDSV*)(ldsA##nb + 4096), 16, 0, 0); \
        __builtin_amdgcn_global_load_lds((CGV*)(bSrc0 + (k0)), (LDSV*)(ldsB##nb), 16, 0, 0);        \
        __builtin_amdgcn_global_load_lds((CGV*)(bSrc1 + (k0)), (LDSV*)(ldsB##nb + 4096), 16, 0, 0); \
    } while (0)

#define COMPUTE(nb)                                                                    \
    do {                                                                               \
        bh8 af[4], bf[4];                                                              \
        _Pragma("unroll")                                                              \
        for (int m = 0; m < 4; m++) af[m] = *(const bh8*)&As[nb][offA[m]];             \
        _Pragma("unroll")                                                              \
        for (int n = 0; n < 4; n++) bf[n] = *(const bh8*)&Bs[nb][offB[n]];             \
        _Pragma("unroll")                                                              \
        for (int m = 0; m < 4; m++)                                                    \
            _Pragma("unroll")                                                          \
            for (int n = 0; n < 4; n++)                                                \
                acc[m][n] = __builtin_amdgcn_mfma_f32_16x16x32_bf16(af[m], bf[n],      \
                                                                    acc[m][n], 0, 0, 0); \
    } while (0)

#define VM0 asm volatile("s_waitcnt vmcnt(0)" ::: "memory")
#define BARR __builtin_amdgcn_s_barrier()

    #pragma unroll 1
    for (int c = 0; c < CPB; ++c) {
        const int colBase = colBase0 + c * BN;
        const unsigned short* bSrc0 = wh + (size_t)(colBase + rr) * KP + csw * 8;
        const unsigned short* bSrc1 = bSrc0 + (size_t)64 * KP;

        fx4 acc[4][4];
        #pragma unroll
        for (int m = 0; m < 4; m++)
            #pragma unroll
            for (int n = 0; n < 4; n++) acc[m][n] = (fx4)0.f;

        STAGE(0, 0);
        VM0; BARR;
        #pragma unroll 1
        for (int t = 0; t < KT - 1; t += 2) {   // KT=25 odd: stages tiles 1..24
            STAGE(1, (t + 1) * BK);
            COMPUTE(0);
            VM0; BARR;
            STAGE(0, (t + 2) * BK);
            COMPUTE(1);
            VM0; BARR;
        }
        COMPUTE(0);   // tile KT-1

        // epilogue: fold this chunk into register top-2
        const int cb = colBase + waveN + (lane & 15);
        #pragma unroll
        for (int n = 0; n < 4; n++) {
            const float wq = wsq[cb + n * 16];
            const int ci = cb + n * 16;
            #pragma unroll
            for (int m = 0; m < 4; m++)
                #pragma unroll
                for (int r = 0; r < 4; r++) {
                    float dv = wq - 2.f * acc[m][n][r];
                    top2_insert(dv, ci, V0[m * 4 + r], I0[m * 4 + r],
                                V1[m * 4 + r], I1[m * 4 + r]);
                }
        }
        __syncthreads();   // all reads of buf0 done before next chunk restages
    }

#undef STAGE
#undef COMPUTE
#undef VM0
#undef BARR

    // cross-lane reduce (once per block) + cross-wave combine
    #pragma unroll
    for (int q = 0; q < 16; q++) {
        float v0 = V0[q], v1 = V1[q];
        int i0 = I0[q], i1 = I1[q];
        #pragma unroll
        for (int mask = 1; mask < 16; mask <<= 1) {
            float w0 = __shfl_xor(v0, mask); int j0 = __shfl_xor(i0, mask);
            float w1 = __shfl_xor(v1, mask); int j1 = __shfl_xor(i1, mask);
            top2_insert(w0, j0, v0, i0, v1, i1);
            top2_insert(w1, j1, v0, i0, v1, i1);
        }
        if ((lane & 15) == 0) {
            int m = q >> 2, r = q & 3;
            int row_local = waveM + m * 16 + (lane >> 4) * 4 + r;
            red[row_local][wid & 1] =
                make_float4(v0, __int_as_float(i0), v1, __int_as_float(i1));
        }
    }
    __syncthreads();
    if (tid < BM) {
        float4 pa = red[tid][0], pb = red[tid][1];
        float v0 = pa.x, v1 = pa.z;
        int i0 = __float_as_int(pa.y), i1 = __float_as_int(pa.w);
        top2_insert(pb.x, __float_as_int(pb.y), v0, i0, v1, i1);
        top2_insert(pb.z, __float_as_int(pb.w), v0, i0, v1, i1);
        partial[(size_t)(rowBase + tid) * NG + bx] =
            make_float4(v0, __int_as_float(i0), v1, __int_as_float(i1));
    }
}

// ---------------------------------------------------------------------------
// Rescue: fp64 rescore of all candidates within MARGIN of approx global min.
// ---------------------------------------------------------------------------
__global__ __launch_bounds__(256) void rescore_kernel(const float* __restrict__ x,
                                                      const float* __restrict__ w,
                                                      const float4* __restrict__ partial,
                                                      float* __restrict__ out) {
    int wid = threadIdx.x >> 6, lane = threadIdx.x & 63;
    int row = blockIdx.x * 4 + wid;
    __shared__ int s_cnt[4];
    __shared__ int s_cand[4][64];

    const float4* part = partial + (size_t)row * NG;

    float bv = INFINITY;
    for (int c = lane; c < NG; c += 64) bv = fminf(bv, part[c].x);
    #pragma unroll
    for (int mask = 1; mask < 64; mask <<= 1) bv = fminf(bv, __shfl_xor(bv, mask));
    float thr = bv + MARGIN;

    if (lane == 0) s_cnt[wid] = 0;
    __syncthreads();
    for (int c = lane; c < NG; c += 64) {
        float4 p = part[c];
        if (p.x <= thr) {
            int pos = atomicAdd(&s_cnt[wid], 1);
            if (pos < 64) s_cand[wid][pos] = __float_as_int(p.y);
        }
        if (p.z <= thr) {
            int pos = atomicAdd(&s_cnt[wid], 1);
            if (pos < 64) s_cand[wid][pos] = __float_as_int(p.w);
        }
    }
    __syncthreads();
    int cnt = s_cnt[wid]; if (cnt > 64) cnt = 64;

    double bd = INFINITY; int bi = 0x7fffffff;
    for (int c = 0; c < cnt; c++) {
        int idx = s_cand[wid][c];
        const float* wr = w + (size_t)idx * D;
        const float* xr = x + (size_t)row * D;
        double s = 0.0;
        for (int d = lane; d < D; d += 64) {
            double wv = (double)wr[d];
            s += wv * (wv - 2.0 * (double)xr[d]);
        }
        #pragma unroll
        for (int mask = 1; mask < 64; mask <<= 1) s += __shfl_xor(s, mask);
        if (s < bd || (s == bd && idx < bi)) { bd = s; bi = idx; }
    }

    const float4* src = (const float4*)(w + (size_t)bi * D);
    float4* dst = (float4*)(out + (size_t)row * D);
    for (int i = lane; i < D / 4; i += 64) dst[i] = src[i];
}

// ---------------------------------------------------------------------------
extern "C" void kernel_launch(void* const* d_in, const int* in_sizes, int n_in,
                              void* d_out, int out_size, void* d_ws, size_t ws_size,
                              hipStream_t stream) {
    const float* x = (const float*)d_in[0];
    const float* w = (const float*)d_in[1];
    float* out = (float*)d_out;

    const size_t off_xh = 0;
    const size_t off_wh = off_xh + (size_t)BATCH * KP * 2;     // 6,553,600
    const size_t off_wsq = off_wh + (size_t)NPAD * KP * 2;     // +16,384,000
    const size_t off_part = off_wsq + (size_t)NPAD * 4;        // +40,960
    // need = off_part + 4096*20*16 = 24,289,280 bytes

    unsigned short* xh = (unsigned short*)((char*)d_ws + off_xh);
    unsigned short* wh = (unsigned short*)((char*)d_ws + off_wh);
    float* wsq = (float*)((char*)d_ws + off_wsq);
    float4* partial = (float4*)((char*)d_ws + off_part);

    hipLaunchKernelGGL(convert_x_kernel, dim3(BATCH), dim3(256), 0, stream, x, xh);
    hipLaunchKernelGGL(convert_w_kernel, dim3(NPAD), dim3(256), 0, stream, w, wh, wsq);
    hipLaunchKernelGGL(dist_mfma_kernel, dim3(GX, BATCH / BM), dim3(256), 0, stream,
                       xh, wh, wsq, partial);
    hipLaunchKernelGGL(rescore_kernel, dim3(BATCH / 4), dim3(256), 0, stream,
                       x, w, partial, out);
}